// Round 6
// baseline (227.863 us; speedup 1.0000x reference)
//
#include <hip/hip_runtime.h>

// Problem constants
#define BB 8
#define TT 1024
#define NH 8
#define HD 64
#define QT 128   // q rows per attention block (R12 proven structure)

typedef unsigned short u16;
typedef __attribute__((ext_vector_type(8))) short bf16x8;
typedef __attribute__((ext_vector_type(16))) float f32x16;

__device__ __forceinline__ float bf2f(u16 s) {
    union { unsigned u; float f; } v; v.u = ((unsigned)s) << 16; return v.f;
}
__device__ __forceinline__ u16 f2bf(float f) {
    union { float f; unsigned u; } v; v.f = f;
    unsigned r = (v.u + 0x7FFFu + ((v.u >> 16) & 1u)) >> 16;
    return (u16)r;
}
__device__ __forceinline__ float bperm(int byte_idx, float v) {
    union { float f; int i; } a; a.f = v;
    union { int i; float f; } b;
    b.i = __builtin_amdgcn_ds_bpermute(byte_idx, a.i);
    return b.f;
}
// async global->LDS, 16B/lane. LDS dest = wave-uniform base + lane*16.
__device__ __forceinline__ void gload_lds16(const u16* g, u16* l) {
    __builtin_amdgcn_global_load_lds(
        (const __attribute__((address_space(1))) unsigned int*)g,
        (__attribute__((address_space(3))) unsigned int*)l, 16, 0, 0);
}

#define MFMA(a, b, c) __builtin_amdgcn_mfma_f32_32x32x16_bf16((a), (b), (c), 0, 0, 0)

// ---------------------------------------------------------------------------
// Flat fp32 -> bf16 for x (4,194,304 elems) and rel_emb (65,600 elems).
// ---------------------------------------------------------------------------
#define NX4 1048576   // x float4 chunks
#define NR4 16400     // rel float4 chunks
__global__ void cvt_misc(const float* __restrict__ x, const float* __restrict__ rel,
                         u16* __restrict__ xb, u16* __restrict__ relb)
{
    size_t i = (size_t)blockIdx.x * 256 + threadIdx.x;
    const float* src; u16* dst;
    if (i < NX4) { src = x; dst = xb; }
    else {
        i -= NX4;
        if (i >= NR4) return;
        src = rel; dst = relb;
    }
    float4 f = *(const float4*)(src + i * 4);
    ushort4 o;
    o.x = f2bf(f.x); o.y = f2bf(f.y); o.z = f2bf(f.z); o.w = f2bf(f.w);
    *(ushort4*)(dst + i * 4) = o;
}

// ---------------------------------------------------------------------------
// Transpose W [512, N] fp32 -> W^T [N, 512] bf16 (Wq, Wkv, Wout in one grid).
// WqT and WkvT are laid out contiguously (WT_all[1536][512]).
// ---------------------------------------------------------------------------
__global__ __launch_bounds__(256) void cvt_wT(
    const float* __restrict__ Wq, const float* __restrict__ Wkv,
    const float* __restrict__ Wout,
    u16* __restrict__ WqT, u16* __restrict__ WkvT, u16* __restrict__ WoutT)
{
    __shared__ float tile[64][65];
    int bid = blockIdx.x;
    const float* W; u16* Wt; int N, kt, ct;
    if (bid < 64)       { W = Wq;   Wt = WqT;   N = 512;  kt = (bid >> 3) * 64; ct = (bid & 7) * 64; }
    else if (bid < 192) { bid -= 64;  W = Wkv;  Wt = WkvT; N = 1024; kt = (bid >> 4) * 64; ct = (bid & 15) * 64; }
    else                { bid -= 192; W = Wout; Wt = WoutT; N = 512;  kt = (bid >> 3) * 64; ct = (bid & 7) * 64; }

    const int tid = threadIdx.x;
#pragma unroll
    for (int i = 0; i < 16; i++) {
        int e = tid + i * 256;
        int r = e >> 6, c = e & 63;
        tile[r][c] = W[(size_t)(kt + r) * N + ct + c];
    }
    __syncthreads();
#pragma unroll
    for (int i = 0; i < 16; i++) {
        int e = tid + i * 256;
        int rr = e >> 6, cc = e & 63;   // output row = original col
        Wt[(size_t)(ct + rr) * 512 + kt + cc] = f2bf(tile[cc][rr]);
    }
}

// ---------------------------------------------------------------------------
// R17 GEMM K-loop core (shared by gemm_qkv / gemm_out):
// m97-style LDS staging. Block = 128x128 tile, 4 waves 2x2 of 64x64,
// acc[2][2] of 32x32 MFMA. K staged in 64-wide steps:
//   - global_load_lds width=16: coalesced, zero-VGPR staging.
//   - LDS XOR swizzle (rule 21: pre-swizzled SOURCE + swizzled READ).
//   - 2-barrier loop; __syncthreads provides the vmcnt drain.
// ---------------------------------------------------------------------------
#define GEMM_STAGE(As, Bs, Abase, Bbase, k0)                                   \
    {                                                                          \
        const int wb16 = (tid & 192) * 8; /* wave base, u16 units (64*16B) */  \
        _Pragma("unroll")                                                      \
        for (int i = 0; i < 4; i++) {                                          \
            int slot = i * 256 + tid;                                          \
            int row = slot >> 3;                                               \
            int c16 = (slot & 7) ^ (row & 7);                                  \
            gload_lds16(Abase + (size_t)row * 512 + (k0) + c16 * 8,            \
                        As + i * 2048 + wb16);                                 \
            gload_lds16(Bbase + (size_t)row * 512 + (k0) + c16 * 8,            \
                        Bs + i * 2048 + wb16);                                 \
        }                                                                      \
    }

#define GEMM_COMPUTE(As, Bs, ar_base, br_base)                                 \
    {                                                                          \
        _Pragma("unroll")                                                      \
        for (int ks = 0; ks < 4; ks++) {                                       \
            bf16x8 a0, a1, b0, b1;                                             \
            {                                                                  \
                int r0_ = (ar_base), r1_ = (ar_base) + 32;                     \
                int q0_ = (br_base), q1_ = (br_base) + 32;                     \
                a0 = *(const bf16x8*)(As + r0_ * 64 +                          \
                                      (((2 * ks + lh) ^ (r0_ & 7)) * 8));      \
                a1 = *(const bf16x8*)(As + r1_ * 64 +                          \
                                      (((2 * ks + lh) ^ (r1_ & 7)) * 8));      \
                b0 = *(const bf16x8*)(Bs + q0_ * 64 +                          \
                                      (((2 * ks + lh) ^ (q0_ & 7)) * 8));      \
                b1 = *(const bf16x8*)(Bs + q1_ * 64 +                          \
                                      (((2 * ks + lh) ^ (q1_ & 7)) * 8));      \
            }                                                                  \
            acc[0][0] = MFMA(a0, b0, acc[0][0]);                               \
            acc[0][1] = MFMA(a0, b1, acc[0][1]);                               \
            acc[1][0] = MFMA(a1, b0, acc[1][0]);                               \
            acc[1][1] = MFMA(a1, b1, acc[1][1]);                               \
        }                                                                      \
    }

// ---------------------------------------------------------------------------
// Fused qkv projection. Grid (64, 12), block 256. Output split q/k/v with
// the R9-proven epilogue (q scaled 0.125/ln2; v transposed [b,h,d,t]).
// ---------------------------------------------------------------------------
__global__ __launch_bounds__(256) void gemm_qkv(
    const u16* __restrict__ A, const u16* __restrict__ Bt,
    const float* __restrict__ bq, const float* __restrict__ bkv,
    u16* __restrict__ oq, u16* __restrict__ ok, u16* __restrict__ ov)
{
    __shared__ __align__(16) u16 As[128 * 64];
    __shared__ __align__(16) u16 Bs[128 * 64];

    const int tid = threadIdx.x;
    const int lane = tid & 63, w = tid >> 6;
    const int l31 = lane & 31, lh = lane >> 5;
    const int wr = w & 1, wc = w >> 1;
    const int row0 = blockIdx.x * 128 + 64 * wr;
    const int c0g  = blockIdx.y * 128 + 64 * wc;

    const u16* Abase = A  + (size_t)blockIdx.x * 128 * 512;
    const u16* Bbase = Bt + (size_t)blockIdx.y * 128 * 512;
    const int ar_base = 64 * wr + l31;
    const int br_base = 64 * wc + l31;

    f32x16 acc[2][2];
#pragma unroll
    for (int i = 0; i < 2; i++)
#pragma unroll
        for (int j = 0; j < 2; j++)
#pragma unroll
            for (int e = 0; e < 16; e++) acc[i][j][e] = 0.f;

    for (int kk = 0; kk < 8; kk++) {
        GEMM_STAGE(As, Bs, Abase, Bbase, kk * 64);
        __syncthreads();
        GEMM_COMPUTE(As, Bs, ar_base, br_base);
        __syncthreads();
    }

    const int rbase = 4 * lh;
#pragma unroll
    for (int ri = 0; ri < 2; ri++) {
#pragma unroll
        for (int ci = 0; ci < 2; ci++) {
            const int r0 = row0 + 32 * ri;
            const int gc = c0g + 32 * ci + l31;
            if (gc < 512) {            // q (scaled by 0.125 * 1/ln2)
                const float bv = bq[gc];
                const int h = gc >> 6, d = gc & 63;
#pragma unroll
                for (int rg = 0; rg < 16; rg++) {
                    int gr = r0 + (rg & 3) + 8 * (rg >> 2) + rbase;
                    int b = gr >> 10, t = gr & 1023;
                    oq[(((size_t)b * NH + h) * TT + t) * HD + d] =
                        f2bf((acc[ri][ci][rg] + bv) * 0.18033688f);
                }
            } else if (gc < 1024) {    // k
                const float bv = bkv[gc - 512];
                const int h = (gc - 512) >> 6, d = gc & 63;
#pragma unroll
                for (int rg = 0; rg < 16; rg++) {
                    int gr = r0 + (rg & 3) + 8 * (rg >> 2) + rbase;
                    int b = gr >> 10, t = gr & 1023;
                    ok[(((size_t)b * NH + h) * TT + t) * HD + d] =
                        f2bf(acc[ri][ci][rg] + bv);
                }
            } else {                   // v, transposed [b,h,d,t]
                const float bv = bkv[gc - 512];
                const int vcol = gc - 1024;
                const int h = vcol >> 6, d = vcol & 63;
                const int b = r0 >> 10;
                const int t0 = (r0 & 1023) + rbase;
                size_t base = (((size_t)b * NH + h) * HD + d) * TT;
#pragma unroll
                for (int g = 0; g < 4; g++) {
                    ushort4 p;
                    p.x = f2bf(acc[ri][ci][4 * g + 0] + bv);
                    p.y = f2bf(acc[ri][ci][4 * g + 1] + bv);
                    p.z = f2bf(acc[ri][ci][4 * g + 2] + bv);
                    p.w = f2bf(acc[ri][ci][4 * g + 3] + bv);
                    *(ushort4*)&ov[base + t0 + 8 * g] = p;
                }
            }
        }
    }
}

// ---------------------------------------------------------------------------
// Out projection: out = a[8192,512] @ Wout + bout, fp32 result.
// R17: same 128x128 LDS-staged template. Grid (64, 4) = 256 blocks.
// ---------------------------------------------------------------------------
__global__ __launch_bounds__(256) void gemm_out(
    const u16* __restrict__ A, const u16* __restrict__ Bt,
    const float* __restrict__ bias, float* __restrict__ of)
{
    __shared__ __align__(16) u16 As[128 * 64];
    __shared__ __align__(16) u16 Bs[128 * 64];

    const int tid = threadIdx.x;
    const int lane = tid & 63, w = tid >> 6;
    const int l31 = lane & 31, lh = lane >> 5;
    const int wr = w & 1, wc = w >> 1;
    const int row0 = blockIdx.x * 128 + 64 * wr;
    const int c0g  = blockIdx.y * 128 + 64 * wc;

    const u16* Abase = A  + (size_t)blockIdx.x * 128 * 512;
    const u16* Bbase = Bt + (size_t)blockIdx.y * 128 * 512;
    const int ar_base = 64 * wr + l31;
    const int br_base = 64 * wc + l31;

    f32x16 acc[2][2];
#pragma unroll
    for (int i = 0; i < 2; i++)
#pragma unroll
        for (int j = 0; j < 2; j++)
#pragma unroll
            for (int e = 0; e < 16; e++) acc[i][j][e] = 0.f;

    for (int kk = 0; kk < 8; kk++) {
        GEMM_STAGE(As, Bs, Abase, Bbase, kk * 64);
        __syncthreads();
        GEMM_COMPUTE(As, Bs, ar_base, br_base);
        __syncthreads();
    }

    const int rbase = 4 * lh;
#pragma unroll
    for (int ri = 0; ri < 2; ri++) {
#pragma unroll
        for (int ci = 0; ci < 2; ci++) {
            const int gcol = c0g + 32 * ci + l31;
            const float bv = bias[gcol];
#pragma unroll
            for (int rg = 0; rg < 16; rg++) {
                int gr = row0 + 32 * ri + (rg & 3) + 8 * (rg >> 2) + rbase;
                of[(size_t)gr * 512 + gcol] = acc[ri][ci][rg] + bv;
            }
        }
    }
}

// ---------------------------------------------------------------------------
// MFMA flash attention (R16 + R18).
// R18: PHASE DECORRELATION. Counters show wall/tile = 2x per-wave critical
// path with both waves ~72% co-stalled: the SIMD's two co-resident waves run
// identical code launched simultaneously -> lockstep -> every dependency
// stall is taken by BOTH waves together, so TLP hides nothing. The m-tile
// loop is a PURE ADDITIVE stream (li is a plain sum of exps; no running
// max, no rescale) -> tile order is irrelevant. Rotate each block's m-loop
// start by a per-block hash offset so co-resident waves sit in different
// phases (one in its bperm/exp region while the other runs MFMAs). Knuth
// multiplicative hash decorrelates any plausible co-residency stride
// (1/64/256). All prefetch indices wrap mod 16 (wrap loads were already
// issued before as dummies). Zero extra per-tile instructions.
// ---------------------------------------------------------------------------
__global__ __launch_bounds__(256) void attn_mfma(
    const u16* __restrict__ q_ws, const u16* __restrict__ k_ws,
    const u16* __restrict__ v_ws, const u16* __restrict__ relb,
    u16* __restrict__ attn_out)
{
    __shared__ __align__(16) u16 GPs[4][32 * 104];   // per-wave P tile

    const int tid  = threadIdx.x;
    const int lane = tid & 63;
    const int w    = tid >> 6;
    const int l31  = lane & 31;
    const int lh   = lane >> 5;
    const int bh   = blockIdx.x;
    const int n0   = blockIdx.y * QT;

    // R18: per-block phase offset (Knuth hash of linear block id)
    const unsigned lin = blockIdx.y * 64 + blockIdx.x;
    const int off = (int)((lin * 2654435761u) >> 24) & 15;

    // Q A-fragments (rows n0+32w+l31), held in registers for all 16 m-tiles
    bf16x8 a_q[4];
    {
        const u16* qp = q_ws + (((size_t)bh * TT) + n0 + 32 * w + l31) * HD + 8 * lh;
#pragma unroll
        for (int ks = 0; ks < 4; ks++)
            a_q[ks] = *(const bf16x8*)(qp + 16 * ks);
    }

    f32x16 O0, O1;
    float li[16];
#pragma unroll
    for (int i = 0; i < 16; i++) { O0[i] = 0.f; O1[i] = 0.f; li[i] = 0.f; }

    u16* Gw = GPs[w];
    const int rbase = 4 * lh;
    const u16* kbase = k_ws + (size_t)bh * TT * HD;
    const u16* vbase = v_ws + (size_t)bh * HD * TT;
    const int pbb = n0 + 449 + 32 * w;   // rel-pos base for m0 = 0

    // ---- mt-invariant precomputes
    f32x16 zvec;
#pragma unroll
    for (int i = 0; i < 16; i++) zvec[i] = 0.f;
    int bidx16[16];
    float mhi[16], mlo[16];
#pragma unroll
    for (int rg = 0; rg < 16; rg++) {
        int r = (rg & 3) + 8 * (rg >> 2) + rbase;
        bidx16[rg] = (((lh << 5) | ((r - l31 + 31) & 31))) << 2;
        bool hi = r > l31;
        mhi[rg] = hi ? 1.f : 0.f;
        mlo[rg] = hi ? 0.f : 1.f;
    }

    // ---- preloop (tile "off"): kf(off) load+consume -> S(off);
    //      then issue rf(off), kf(off+1)
    bf16x8 kf[8], rf[12];
    {
        const u16* kb = kbase + (size_t)(off * 64) * HD;
#pragma unroll
        for (int ks = 0; ks < 4; ks++) {
            const int doff = 16 * ks + 8 * lh;
            kf[2 * ks]     = *(const bf16x8*)(kb + (size_t)l31 * HD + doff);
            kf[2 * ks + 1] = *(const bf16x8*)(kb + (size_t)(l31 + 32) * HD + doff);
        }
    }
    f32x16 S0 = MFMA(a_q[0], kf[0], zvec);
    f32x16 S1 = MFMA(a_q[0], kf[1], zvec);
#pragma unroll
    for (int ks = 1; ks < 4; ks++) {
        S0 = MFMA(a_q[ks], kf[2 * ks], S0);
        S1 = MFMA(a_q[ks], kf[2 * ks + 1], S1);
    }
    {   // rf(off)
        const int pb = pbb - off * 64;
#pragma unroll
        for (int gt = 0; gt < 3; gt++) {
            int p = pb + 32 * gt + l31;
            p = p < 0 ? 0 : (p > 1024 ? 1024 : p);
            const u16* rb = relb + (size_t)p * HD;
#pragma unroll
            for (int ks = 0; ks < 4; ks++)
                rf[4 * gt + ks] = *(const bf16x8*)(rb + 16 * ks + 8 * lh);
        }
    }
    {   // kf(off+1)
        const u16* kb = kbase + (size_t)(((off + 1) & 15) * 64) * HD;
#pragma unroll
        for (int ks = 0; ks < 4; ks++) {
            const int doff = 16 * ks + 8 * lh;
            kf[2 * ks]     = *(const bf16x8*)(kb + (size_t)l31 * HD + doff);
            kf[2 * ks + 1] = *(const bf16x8*)(kb + (size_t)(l31 + 32) * HD + doff);
        }
    }

    for (int it = 0; it < 16; it++) {
        const int mt = (off + it) & 15;
        const int m0 = mt * 64;
        // On entry: S0/S1 = QK(mt) done; rf = rel(mt) in flight; kf = K(mt+1).

        // ---- G phase, 2-deep pipeline
        f32x16 gA = MFMA(a_q[0], rf[0], zvec);
        f32x16 gB = MFMA(a_q[0], rf[4], zvec);
#pragma unroll
        for (int ks = 1; ks < 4; ks++) {
            gA = MFMA(a_q[ks], rf[ks], gA);
            gB = MFMA(a_q[ks], rf[4 + ks], gB);
        }
#pragma unroll
        for (int rg = 0; rg < 16; rg++) {         // skew gt0 -> S1
            float v = bperm(bidx16[rg], gA[rg]);
            S1[rg] += v * mlo[rg];
        }
        gA = MFMA(a_q[0], rf[8], zvec);           // gt2 chain (reuse gA)
#pragma unroll
        for (int ks = 1; ks < 4; ks++)
            gA = MFMA(a_q[ks], rf[8 + ks], gA);
#pragma unroll
        for (int rg = 0; rg < 16; rg++) {         // skew gt1 -> S0,S1
            float v = bperm(bidx16[rg], gB[rg]);
            S0[rg] += v * mlo[rg];
            S1[rg] += v * mhi[rg];
        }
#pragma unroll
        for (int rg = 0; rg < 16; rg++) {         // skew gt2 -> S0
            float v = bperm(bidx16[rg], gA[rg]);
            S0[rg] += v * mhi[rg];
        }

        // ---- VMEM issue: vf(mt), then rf(next)
        bf16x8 vf[8];
        {
            const u16* vb = vbase + m0;
#pragma unroll
            for (int ms = 0; ms < 4; ms++) {
                const int mg = 2 * ms + lh;
                vf[2 * ms]     = *(const bf16x8*)(vb + (size_t)l31 * TT + mg * 8);
                vf[2 * ms + 1] = *(const bf16x8*)(vb + (size_t)(l31 + 32) * TT + mg * 8);
            }
        }
        {
            const int m0n = ((off + it + 1) & 15) * 64;   // wraps mod 16
            const int pb = pbb - m0n;
#pragma unroll
            for (int gt = 0; gt < 3; gt++) {
                int p = pb + 32 * gt + l31;
                p = p < 0 ? 0 : (p > 1024 ? 1024 : p);
                const u16* rb = relb + (size_t)p * HD;
#pragma unroll
                for (int ks = 0; ks < 4; ks++)
                    rf[4 * gt + ks] = *(const bf16x8*)(rb + 16 * ks + 8 * lh);
            }
        }

        // ---- streaming softmax + P pack (q pre-scaled by 1/ln2 -> 2^x)
#pragma unroll
        for (int rg = 0; rg < 16; rg++) {
            float e0, e1;
            asm("v_exp_f32 %0, %1" : "=v"(e0) : "v"(S0[rg]));
            asm("v_exp_f32 %0, %1" : "=v"(e1) : "v"(S1[rg]));
            li[rg] += e0 + e1;
            unsigned pk;
            asm("v_cvt_pk_bf16_f32 %0, %1, %2" : "=v"(pk) : "v"(e0), "v"(e1));
            int r = (rg & 3) + 8 * (rg >> 2) + rbase;
            Gw[r * 104 + (((l31 >> 3) ^ (r & 7)) * 8) + (l31 & 7)] = (u16)pk;
            Gw[r * 104 + (((((l31 + 32) >> 3)) ^ (r & 7)) * 8) + (l31 & 7)] =
                (u16)(pk >> 16);
        }

        // ---- S(next) = QK(kf): overlaps softmax/pack + PV LDS turnaround
        if (it < 15) {
            __builtin_amdgcn_s_setprio(1);
            S0 = MFMA(a_q[0], kf[0], zvec);
            S1 = MFMA(a_q[0], kf[1], zvec);
#pragma unroll
            for (int ks = 1; ks < 4; ks++) {
                S0 = MFMA(a_q[ks], kf[2 * ks], S0);
                S1 = MFMA(a_q[ks], kf[2 * ks + 1], S1);
            }
            __builtin_amdgcn_s_setprio(0);
            // issue kf(next+1)
            const int m0k = ((off + it + 2) & 15) * 64;   // wraps mod 16
            const u16* kb = kbase + (size_t)m0k * HD;
#pragma unroll
            for (int ks = 0; ks < 4; ks++) {
                const int doff = 16 * ks + 8 * lh;
                kf[2 * ks]     = *(const bf16x8*)(kb + (size_t)l31 * HD + doff);
                kf[2 * ks + 1] = *(const bf16x8*)(kb + (size_t)(l31 + 32) * HD + doff);
            }
        }

        // ---- O += P V from vf (waits vf; rf/kf prefetches stay in flight)
        __builtin_amdgcn_s_setprio(1);
#pragma unroll
        for (int ms = 0; ms < 4; ms++) {
            const int mg = 2 * ms + lh;
            bf16x8 a_p = *(const bf16x8*)&Gw[l31 * 104 + ((mg ^ (l31 & 7)) * 8)];
            O0 = MFMA(a_p, vf[2 * ms], O0);
            O1 = MFMA(a_p, vf[2 * ms + 1], O1);
        }
        __builtin_amdgcn_s_setprio(0);
    }

    // ---- epilogue: reduce li across the 32 lanes holding each row
#pragma unroll
    for (int rg = 0; rg < 16; rg++) {
        float rs = li[rg];
        rs += __shfl_xor(rs, 1);
        rs += __shfl_xor(rs, 2);
        rs += __shfl_xor(rs, 4);
        rs += __shfl_xor(rs, 8);
        rs += __shfl_xor(rs, 16);
        li[rg] = 1.0f / rs;
    }

    // write bf16 [b, t, h*64 + d]
    const int b = bh >> 3, h = bh & 7;
    u16* ob = attn_out + ((size_t)b * TT + n0 + 32 * w) * 512 + h * 64;
#pragma unroll
    for (int rg = 0; rg < 16; rg++) {
        int r = (rg & 3) + 8 * (rg >> 2) + rbase;
        ob[(size_t)r * 512 + l31]      = f2bf(O0[rg] * li[rg]);
        ob[(size_t)r * 512 + l31 + 32] = f2bf(O1[rg] * li[rg]);
    }
}

// ---------------------------------------------------------------------------
// Workspace layout (43 MB total — inside the PROVEN 44 MB envelope).
//   [ 0, 8)  q_wsb
//   [ 8,16)  k_wsb
//   [16,24)  v_wsb
//   [24,32)  x_bf (dead after gemm_qkv)
//   [32,40)  a_wsb (bf16 [b,t,512], written directly by attn)
//   [40,40.5) relb
//   [41,42.5) WT_all    [42.5,43) WoutT
// ---------------------------------------------------------------------------
extern "C" void kernel_launch(void* const* d_in, const int* in_sizes, int n_in,
                              void* d_out, int out_size, void* d_ws, size_t ws_size,
                              hipStream_t stream)
{
    const float* x    = (const float*)d_in[0];
    const float* Wq   = (const float*)d_in[1];
    const float* bq   = (const float*)d_in[2];
    const float* Wkv  = (const float*)d_in[3];
    const float* bkv  = (const float*)d_in[4];
    const float* Wout = (const float*)d_in[5];
    const float* bout = (const float*)d_in[6];
    const float* rel  = (const float*)d_in[7];
    float* out = (float*)d_out;

    char* ws = (char*)d_ws;
    const size_t MB = 1024 * 1024;
    u16*   q_wsb  = (u16*)(ws);                           // 8 MB [b,h,t,d]
    u16*   k_wsb  = (u16*)(ws + 8 * MB);                  // 8 MB [b,h,t,d]
    u16*   v_wsb  = (u16*)(ws + 16 * MB);                 // 8 MB [b,h,d,t]
    u16*   x_bf   = (u16*)(ws + 24 * MB);                 // 8 MB [8192,512]
    u16*   a_wsb  = (u16*)(ws + 32 * MB);                 // 8 MB [b,t,512]
    u16*   relb   = (u16*)(ws + 40 * MB);                 // 128 KB
    u16*   WT_all = (u16*)(ws + 41 * MB);                 // 1.5 MB [1536,512]
    u16*   WoutT  = (u16*)(ws + 42 * MB + 512 * 1024);    // 512 KB [512,512]

    // A: dtype conversions
    cvt_misc<<<(NX4 + NR4 + 255) / 256, 256, 0, stream>>>(x, rel, x_bf, relb);
    cvt_wT<<<256, 256, 0, stream>>>(Wq, Wkv, Wout, WT_all, WT_all + 512 * 512, WoutT);

    // B: fused qkv projection, LDS-staged m97-style (R17)
    gemm_qkv<<<dim3(64, 12), 256, 0, stream>>>(
        x_bf, WT_all, bq, bkv, q_wsb, k_wsb, v_wsb);

    // C: attention, phase-decorrelated m-loop (R18)
    attn_mfma<<<dim3(64, 8), 256, 0, stream>>>(
        q_wsb, k_wsb, v_wsb, relb, a_wsb);

    // D: out projection, LDS-staged m97-style (R17)
    gemm_out<<<dim3(64, 4), 256, 0, stream>>>(a_wsb, WoutT, bout, out);
}

// Round 7
// 222.395 us; speedup vs baseline: 1.0246x; 1.0246x over previous
//
#include <hip/hip_runtime.h>

// Problem constants
#define BB 8
#define TT 1024
#define NH 8
#define HD 64
#define QT 128   // q rows per attention block (R12 proven structure)

typedef unsigned short u16;
typedef __attribute__((ext_vector_type(8))) short bf16x8;
typedef __attribute__((ext_vector_type(16))) float f32x16;

__device__ __forceinline__ float bf2f(u16 s) {
    union { unsigned u; float f; } v; v.u = ((unsigned)s) << 16; return v.f;
}
__device__ __forceinline__ u16 f2bf(float f) {
    union { float f; unsigned u; } v; v.f = f;
    unsigned r = (v.u + 0x7FFFu + ((v.u >> 16) & 1u)) >> 16;
    return (u16)r;
}
__device__ __forceinline__ float bperm(int byte_idx, float v) {
    union { float f; int i; } a; a.f = v;
    union { int i; float f; } b;
    b.i = __builtin_amdgcn_ds_bpermute(byte_idx, a.i);
    return b.f;
}
// async global->LDS, 16B/lane. LDS dest = wave-uniform base + lane*16.
__device__ __forceinline__ void gload_lds16(const u16* g, u16* l) {
    __builtin_amdgcn_global_load_lds(
        (const __attribute__((address_space(1))) unsigned int*)g,
        (__attribute__((address_space(3))) unsigned int*)l, 16, 0, 0);
}

#define MFMA(a, b, c) __builtin_amdgcn_mfma_f32_32x32x16_bf16((a), (b), (c), 0, 0, 0)

// ---------------------------------------------------------------------------
// Flat fp32 -> bf16 for x (4,194,304 elems) and rel_emb (65,600 elems).
// ---------------------------------------------------------------------------
#define NX4 1048576   // x float4 chunks
#define NR4 16400     // rel float4 chunks
__global__ void cvt_misc(const float* __restrict__ x, const float* __restrict__ rel,
                         u16* __restrict__ xb, u16* __restrict__ relb)
{
    size_t i = (size_t)blockIdx.x * 256 + threadIdx.x;
    const float* src; u16* dst;
    if (i < NX4) { src = x; dst = xb; }
    else {
        i -= NX4;
        if (i >= NR4) return;
        src = rel; dst = relb;
    }
    float4 f = *(const float4*)(src + i * 4);
    ushort4 o;
    o.x = f2bf(f.x); o.y = f2bf(f.y); o.z = f2bf(f.z); o.w = f2bf(f.w);
    *(ushort4*)(dst + i * 4) = o;
}

// ---------------------------------------------------------------------------
// Transpose W [512, N] fp32 -> W^T [N, 512] bf16 (Wq, Wkv, Wout in one grid).
// WqT and WkvT are laid out contiguously (WT_all[1536][512]).
// ---------------------------------------------------------------------------
__global__ __launch_bounds__(256) void cvt_wT(
    const float* __restrict__ Wq, const float* __restrict__ Wkv,
    const float* __restrict__ Wout,
    u16* __restrict__ WqT, u16* __restrict__ WkvT, u16* __restrict__ WoutT)
{
    __shared__ float tile[64][65];
    int bid = blockIdx.x;
    const float* W; u16* Wt; int N, kt, ct;
    if (bid < 64)       { W = Wq;   Wt = WqT;   N = 512;  kt = (bid >> 3) * 64; ct = (bid & 7) * 64; }
    else if (bid < 192) { bid -= 64;  W = Wkv;  Wt = WkvT; N = 1024; kt = (bid >> 4) * 64; ct = (bid & 15) * 64; }
    else                { bid -= 192; W = Wout; Wt = WoutT; N = 512;  kt = (bid >> 3) * 64; ct = (bid & 7) * 64; }

    const int tid = threadIdx.x;
#pragma unroll
    for (int i = 0; i < 16; i++) {
        int e = tid + i * 256;
        int r = e >> 6, c = e & 63;
        tile[r][c] = W[(size_t)(kt + r) * N + ct + c];
    }
    __syncthreads();
#pragma unroll
    for (int i = 0; i < 16; i++) {
        int e = tid + i * 256;
        int rr = e >> 6, cc = e & 63;   // output row = original col
        Wt[(size_t)(ct + rr) * 512 + kt + cc] = f2bf(tile[cc][rr]);
    }
}

// ---------------------------------------------------------------------------
// R17 GEMM K-loop core (shared by gemm_qkv / gemm_out):
// m97-style LDS staging. Block = 128x128 tile, 4 waves 2x2 of 64x64,
// acc[2][2] of 32x32 MFMA. K staged in 64-wide steps:
//   - global_load_lds width=16: coalesced, zero-VGPR staging.
//   - LDS XOR swizzle (rule 21: pre-swizzled SOURCE + swizzled READ).
//   - 2-barrier loop; __syncthreads provides the vmcnt drain.
// ---------------------------------------------------------------------------
#define GEMM_STAGE(As, Bs, Abase, Bbase, k0)                                   \
    {                                                                          \
        const int wb16 = (tid & 192) * 8; /* wave base, u16 units (64*16B) */  \
        _Pragma("unroll")                                                      \
        for (int i = 0; i < 4; i++) {                                          \
            int slot = i * 256 + tid;                                          \
            int row = slot >> 3;                                               \
            int c16 = (slot & 7) ^ (row & 7);                                  \
            gload_lds16(Abase + (size_t)row * 512 + (k0) + c16 * 8,            \
                        As + i * 2048 + wb16);                                 \
            gload_lds16(Bbase + (size_t)row * 512 + (k0) + c16 * 8,            \
                        Bs + i * 2048 + wb16);                                 \
        }                                                                      \
    }

#define GEMM_COMPUTE(As, Bs, ar_base, br_base)                                 \
    {                                                                          \
        _Pragma("unroll")                                                      \
        for (int ks = 0; ks < 4; ks++) {                                       \
            bf16x8 a0, a1, b0, b1;                                             \
            {                                                                  \
                int r0_ = (ar_base), r1_ = (ar_base) + 32;                     \
                int q0_ = (br_base), q1_ = (br_base) + 32;                     \
                a0 = *(const bf16x8*)(As + r0_ * 64 +                          \
                                      (((2 * ks + lh) ^ (r0_ & 7)) * 8));      \
                a1 = *(const bf16x8*)(As + r1_ * 64 +                          \
                                      (((2 * ks + lh) ^ (r1_ & 7)) * 8));      \
                b0 = *(const bf16x8*)(Bs + q0_ * 64 +                          \
                                      (((2 * ks + lh) ^ (q0_ & 7)) * 8));      \
                b1 = *(const bf16x8*)(Bs + q1_ * 64 +                          \
                                      (((2 * ks + lh) ^ (q1_ & 7)) * 8));      \
            }                                                                  \
            acc[0][0] = MFMA(a0, b0, acc[0][0]);                               \
            acc[0][1] = MFMA(a0, b1, acc[0][1]);                               \
            acc[1][0] = MFMA(a1, b0, acc[1][0]);                               \
            acc[1][1] = MFMA(a1, b1, acc[1][1]);                               \
        }                                                                      \
    }

// ---------------------------------------------------------------------------
// Fused qkv projection. Grid (64, 12), block 256. Output split q/k/v with
// the R9-proven epilogue (q scaled 0.125/ln2; v transposed [b,h,d,t]).
// ---------------------------------------------------------------------------
__global__ __launch_bounds__(256) void gemm_qkv(
    const u16* __restrict__ A, const u16* __restrict__ Bt,
    const float* __restrict__ bq, const float* __restrict__ bkv,
    u16* __restrict__ oq, u16* __restrict__ ok, u16* __restrict__ ov)
{
    __shared__ __align__(16) u16 As[128 * 64];
    __shared__ __align__(16) u16 Bs[128 * 64];

    const int tid = threadIdx.x;
    const int lane = tid & 63, w = tid >> 6;
    const int l31 = lane & 31, lh = lane >> 5;
    const int wr = w & 1, wc = w >> 1;
    const int row0 = blockIdx.x * 128 + 64 * wr;
    const int c0g  = blockIdx.y * 128 + 64 * wc;

    const u16* Abase = A  + (size_t)blockIdx.x * 128 * 512;
    const u16* Bbase = Bt + (size_t)blockIdx.y * 128 * 512;
    const int ar_base = 64 * wr + l31;
    const int br_base = 64 * wc + l31;

    f32x16 acc[2][2];
#pragma unroll
    for (int i = 0; i < 2; i++)
#pragma unroll
        for (int j = 0; j < 2; j++)
#pragma unroll
            for (int e = 0; e < 16; e++) acc[i][j][e] = 0.f;

    for (int kk = 0; kk < 8; kk++) {
        GEMM_STAGE(As, Bs, Abase, Bbase, kk * 64);
        __syncthreads();
        GEMM_COMPUTE(As, Bs, ar_base, br_base);
        __syncthreads();
    }

    const int rbase = 4 * lh;
#pragma unroll
    for (int ri = 0; ri < 2; ri++) {
#pragma unroll
        for (int ci = 0; ci < 2; ci++) {
            const int r0 = row0 + 32 * ri;
            const int gc = c0g + 32 * ci + l31;
            if (gc < 512) {            // q (scaled by 0.125 * 1/ln2)
                const float bv = bq[gc];
                const int h = gc >> 6, d = gc & 63;
#pragma unroll
                for (int rg = 0; rg < 16; rg++) {
                    int gr = r0 + (rg & 3) + 8 * (rg >> 2) + rbase;
                    int b = gr >> 10, t = gr & 1023;
                    oq[(((size_t)b * NH + h) * TT + t) * HD + d] =
                        f2bf((acc[ri][ci][rg] + bv) * 0.18033688f);
                }
            } else if (gc < 1024) {    // k
                const float bv = bkv[gc - 512];
                const int h = (gc - 512) >> 6, d = gc & 63;
#pragma unroll
                for (int rg = 0; rg < 16; rg++) {
                    int gr = r0 + (rg & 3) + 8 * (rg >> 2) + rbase;
                    int b = gr >> 10, t = gr & 1023;
                    ok[(((size_t)b * NH + h) * TT + t) * HD + d] =
                        f2bf(acc[ri][ci][rg] + bv);
                }
            } else {                   // v, transposed [b,h,d,t]
                const float bv = bkv[gc - 512];
                const int vcol = gc - 1024;
                const int h = vcol >> 6, d = vcol & 63;
                const int b = r0 >> 10;
                const int t0 = (r0 & 1023) + rbase;
                size_t base = (((size_t)b * NH + h) * HD + d) * TT;
#pragma unroll
                for (int g = 0; g < 4; g++) {
                    ushort4 p;
                    p.x = f2bf(acc[ri][ci][4 * g + 0] + bv);
                    p.y = f2bf(acc[ri][ci][4 * g + 1] + bv);
                    p.z = f2bf(acc[ri][ci][4 * g + 2] + bv);
                    p.w = f2bf(acc[ri][ci][4 * g + 3] + bv);
                    *(ushort4*)&ov[base + t0 + 8 * g] = p;
                }
            }
        }
    }
}

// ---------------------------------------------------------------------------
// Out projection: out = a[8192,512] @ Wout + bout, fp32 result.
// R17: same 128x128 LDS-staged template. Grid (64, 4) = 256 blocks.
// ---------------------------------------------------------------------------
__global__ __launch_bounds__(256) void gemm_out(
    const u16* __restrict__ A, const u16* __restrict__ Bt,
    const float* __restrict__ bias, float* __restrict__ of)
{
    __shared__ __align__(16) u16 As[128 * 64];
    __shared__ __align__(16) u16 Bs[128 * 64];

    const int tid = threadIdx.x;
    const int lane = tid & 63, w = tid >> 6;
    const int l31 = lane & 31, lh = lane >> 5;
    const int wr = w & 1, wc = w >> 1;
    const int row0 = blockIdx.x * 128 + 64 * wr;
    const int c0g  = blockIdx.y * 128 + 64 * wc;

    const u16* Abase = A  + (size_t)blockIdx.x * 128 * 512;
    const u16* Bbase = Bt + (size_t)blockIdx.y * 128 * 512;
    const int ar_base = 64 * wr + l31;
    const int br_base = 64 * wc + l31;

    f32x16 acc[2][2];
#pragma unroll
    for (int i = 0; i < 2; i++)
#pragma unroll
        for (int j = 0; j < 2; j++)
#pragma unroll
            for (int e = 0; e < 16; e++) acc[i][j][e] = 0.f;

    for (int kk = 0; kk < 8; kk++) {
        GEMM_STAGE(As, Bs, Abase, Bbase, kk * 64);
        __syncthreads();
        GEMM_COMPUTE(As, Bs, ar_base, br_base);
        __syncthreads();
    }

    const int rbase = 4 * lh;
#pragma unroll
    for (int ri = 0; ri < 2; ri++) {
#pragma unroll
        for (int ci = 0; ci < 2; ci++) {
            const int gcol = c0g + 32 * ci + l31;
            const float bv = bias[gcol];
#pragma unroll
            for (int rg = 0; rg < 16; rg++) {
                int gr = row0 + 32 * ri + (rg & 3) + 8 * (rg >> 2) + rbase;
                of[(size_t)gr * 512 + gcol] = acc[ri][ci][rg] + bv;
            }
        }
    }
}

// ---------------------------------------------------------------------------
// MFMA flash attention (R16 + R19).
// R19: MERGED-BPERM SINGLE-EPOCH SKEW. R18's decorrelation was null ->
// the wall is the per-wave serial chain. The old skew was 3 serialized
// {G-chain -> bperm-epoch} phases (48 bperms, only 32 values used).
// Key fact: r = f(rg, lh) is UNIFORM across each 32-lane half, and the
// gather source lane x = (r - c + 31) & 31 wraps exactly when the target
// needs the "wrapped" gt: x >= r <-> requester needs {gt1 for S0, gt0
// for S1}; x < r <-> {gt2 for S0, gt1 for S1}. So select IN THE SOURCE
// LANE before the shuffle:
//     mS0 = (l31 >= r) ? gB : gC;   mS1 = (l31 >= r) ? gA : gB;
//     S0 += bperm(mS0);             S1 += bperm(mS1);
// -> 3 independent G chains (pipeline together, one latency entry), ONE
// 32-bperm epoch, plain adds. Exactly the same selected values as the
// old mlo/mhi fmacs -> absmax must not move (numerics tripwire).
// Cost: gC live (+16 VGPR, ~220 < 256); mhi/mlo freed.
// ---------------------------------------------------------------------------
__global__ __launch_bounds__(256) void attn_mfma(
    const u16* __restrict__ q_ws, const u16* __restrict__ k_ws,
    const u16* __restrict__ v_ws, const u16* __restrict__ relb,
    u16* __restrict__ attn_out)
{
    __shared__ __align__(16) u16 GPs[4][32 * 104];   // per-wave P tile

    const int tid  = threadIdx.x;
    const int lane = tid & 63;
    const int w    = tid >> 6;
    const int l31  = lane & 31;
    const int lh   = lane >> 5;
    const int bh   = blockIdx.x;
    const int n0   = blockIdx.y * QT;

    // per-block phase offset (R18, neutral but harmless; keeps KV L2 spread)
    const unsigned lin = blockIdx.y * 64 + blockIdx.x;
    const int off = (int)((lin * 2654435761u) >> 24) & 15;

    // Q A-fragments (rows n0+32w+l31), held in registers for all 16 m-tiles
    bf16x8 a_q[4];
    {
        const u16* qp = q_ws + (((size_t)bh * TT) + n0 + 32 * w + l31) * HD + 8 * lh;
#pragma unroll
        for (int ks = 0; ks < 4; ks++)
            a_q[ks] = *(const bf16x8*)(qp + 16 * ks);
    }

    f32x16 O0, O1;
    float li[16];
#pragma unroll
    for (int i = 0; i < 16; i++) { O0[i] = 0.f; O1[i] = 0.f; li[i] = 0.f; }

    u16* Gw = GPs[w];
    const int rbase = 4 * lh;
    const u16* kbase = k_ws + (size_t)bh * TT * HD;
    const u16* vbase = v_ws + (size_t)bh * HD * TT;
    const int pbb = n0 + 449 + 32 * w;   // rel-pos base for m0 = 0

    // ---- mt-invariant precomputes
    f32x16 zvec;
#pragma unroll
    for (int i = 0; i < 16; i++) zvec[i] = 0.f;
    int bidx16[16];
#pragma unroll
    for (int rg = 0; rg < 16; rg++) {
        int r = (rg & 3) + 8 * (rg >> 2) + rbase;
        bidx16[rg] = (((lh << 5) | ((r - l31 + 31) & 31))) << 2;
    }

    // ---- preloop (tile "off"): kf(off) load+consume -> S(off);
    //      then issue rf(off), kf(off+1)
    bf16x8 kf[8], rf[12];
    {
        const u16* kb = kbase + (size_t)(off * 64) * HD;
#pragma unroll
        for (int ks = 0; ks < 4; ks++) {
            const int doff = 16 * ks + 8 * lh;
            kf[2 * ks]     = *(const bf16x8*)(kb + (size_t)l31 * HD + doff);
            kf[2 * ks + 1] = *(const bf16x8*)(kb + (size_t)(l31 + 32) * HD + doff);
        }
    }
    f32x16 S0 = MFMA(a_q[0], kf[0], zvec);
    f32x16 S1 = MFMA(a_q[0], kf[1], zvec);
#pragma unroll
    for (int ks = 1; ks < 4; ks++) {
        S0 = MFMA(a_q[ks], kf[2 * ks], S0);
        S1 = MFMA(a_q[ks], kf[2 * ks + 1], S1);
    }
    {   // rf(off)
        const int pb = pbb - off * 64;
#pragma unroll
        for (int gt = 0; gt < 3; gt++) {
            int p = pb + 32 * gt + l31;
            p = p < 0 ? 0 : (p > 1024 ? 1024 : p);
            const u16* rb = relb + (size_t)p * HD;
#pragma unroll
            for (int ks = 0; ks < 4; ks++)
                rf[4 * gt + ks] = *(const bf16x8*)(rb + 16 * ks + 8 * lh);
        }
    }
    {   // kf(off+1)
        const u16* kb = kbase + (size_t)(((off + 1) & 15) * 64) * HD;
#pragma unroll
        for (int ks = 0; ks < 4; ks++) {
            const int doff = 16 * ks + 8 * lh;
            kf[2 * ks]     = *(const bf16x8*)(kb + (size_t)l31 * HD + doff);
            kf[2 * ks + 1] = *(const bf16x8*)(kb + (size_t)(l31 + 32) * HD + doff);
        }
    }

    for (int it = 0; it < 16; it++) {
        const int mt = (off + it) & 15;
        const int m0 = mt * 64;
        // On entry: S0/S1 = QK(mt) done; rf = rel(mt) in flight; kf = K(mt+1).

        // ---- G phase: 3 INDEPENDENT chains, pipelined together
        f32x16 gA = MFMA(a_q[0], rf[0], zvec);
        f32x16 gB = MFMA(a_q[0], rf[4], zvec);
        f32x16 gC = MFMA(a_q[0], rf[8], zvec);
#pragma unroll
        for (int ks = 1; ks < 4; ks++) {
            gA = MFMA(a_q[ks], rf[ks], gA);
            gB = MFMA(a_q[ks], rf[4 + ks], gB);
            gC = MFMA(a_q[ks], rf[8 + ks], gC);
        }

        // ---- merged skew: source-lane select + ONE bperm epoch (32 ops)
#pragma unroll
        for (int rg = 0; rg < 16; rg++) {
            int r = (rg & 3) + 8 * (rg >> 2) + rbase;
            float mS0 = (l31 >= r) ? gB[rg] : gC[rg];
            float mS1 = (l31 >= r) ? gA[rg] : gB[rg];
            S0[rg] += bperm(bidx16[rg], mS0);
            S1[rg] += bperm(bidx16[rg], mS1);
        }

        // ---- VMEM issue: vf(mt), then rf(next)
        bf16x8 vf[8];
        {
            const u16* vb = vbase + m0;
#pragma unroll
            for (int ms = 0; ms < 4; ms++) {
                const int mg = 2 * ms + lh;
                vf[2 * ms]     = *(const bf16x8*)(vb + (size_t)l31 * TT + mg * 8);
                vf[2 * ms + 1] = *(const bf16x8*)(vb + (size_t)(l31 + 32) * TT + mg * 8);
            }
        }
        {
            const int m0n = ((off + it + 1) & 15) * 64;   // wraps mod 16
            const int pb = pbb - m0n;
#pragma unroll
            for (int gt = 0; gt < 3; gt++) {
                int p = pb + 32 * gt + l31;
                p = p < 0 ? 0 : (p > 1024 ? 1024 : p);
                const u16* rb = relb + (size_t)p * HD;
#pragma unroll
                for (int ks = 0; ks < 4; ks++)
                    rf[4 * gt + ks] = *(const bf16x8*)(rb + 16 * ks + 8 * lh);
            }
        }

        // ---- streaming softmax + P pack (q pre-scaled by 1/ln2 -> 2^x)
#pragma unroll
        for (int rg = 0; rg < 16; rg++) {
            float e0, e1;
            asm("v_exp_f32 %0, %1" : "=v"(e0) : "v"(S0[rg]));
            asm("v_exp_f32 %0, %1" : "=v"(e1) : "v"(S1[rg]));
            li[rg] += e0 + e1;
            unsigned pk;
            asm("v_cvt_pk_bf16_f32 %0, %1, %2" : "=v"(pk) : "v"(e0), "v"(e1));
            int r = (rg & 3) + 8 * (rg >> 2) + rbase;
            Gw[r * 104 + (((l31 >> 3) ^ (r & 7)) * 8) + (l31 & 7)] = (u16)pk;
            Gw[r * 104 + (((((l31 + 32) >> 3)) ^ (r & 7)) * 8) + (l31 & 7)] =
                (u16)(pk >> 16);
        }

        // ---- S(next) = QK(kf): overlaps softmax/pack + PV LDS turnaround
        if (it < 15) {
            __builtin_amdgcn_s_setprio(1);
            S0 = MFMA(a_q[0], kf[0], zvec);
            S1 = MFMA(a_q[0], kf[1], zvec);
#pragma unroll
            for (int ks = 1; ks < 4; ks++) {
                S0 = MFMA(a_q[ks], kf[2 * ks], S0);
                S1 = MFMA(a_q[ks], kf[2 * ks + 1], S1);
            }
            __builtin_amdgcn_s_setprio(0);
            // issue kf(next+1)
            const int m0k = ((off + it + 2) & 15) * 64;   // wraps mod 16
            const u16* kb = kbase + (size_t)m0k * HD;
#pragma unroll
            for (int ks = 0; ks < 4; ks++) {
                const int doff = 16 * ks + 8 * lh;
                kf[2 * ks]     = *(const bf16x8*)(kb + (size_t)l31 * HD + doff);
                kf[2 * ks + 1] = *(const bf16x8*)(kb + (size_t)(l31 + 32) * HD + doff);
            }
        }

        // ---- O += P V from vf (waits vf; rf/kf prefetches stay in flight)
        __builtin_amdgcn_s_setprio(1);
#pragma unroll
        for (int ms = 0; ms < 4; ms++) {
            const int mg = 2 * ms + lh;
            bf16x8 a_p = *(const bf16x8*)&Gw[l31 * 104 + ((mg ^ (l31 & 7)) * 8)];
            O0 = MFMA(a_p, vf[2 * ms], O0);
            O1 = MFMA(a_p, vf[2 * ms + 1], O1);
        }
        __builtin_amdgcn_s_setprio(0);
    }

    // ---- epilogue: reduce li across the 32 lanes holding each row
#pragma unroll
    for (int rg = 0; rg < 16; rg++) {
        float rs = li[rg];
        rs += __shfl_xor(rs, 1);
        rs += __shfl_xor(rs, 2);
        rs += __shfl_xor(rs, 4);
        rs += __shfl_xor(rs, 8);
        rs += __shfl_xor(rs, 16);
        li[rg] = 1.0f / rs;
    }

    // write bf16 [b, t, h*64 + d]
    const int b = bh >> 3, h = bh & 7;
    u16* ob = attn_out + ((size_t)b * TT + n0 + 32 * w) * 512 + h * 64;
#pragma unroll
    for (int rg = 0; rg < 16; rg++) {
        int r = (rg & 3) + 8 * (rg >> 2) + rbase;
        ob[(size_t)r * 512 + l31]      = f2bf(O0[rg] * li[rg]);
        ob[(size_t)r * 512 + l31 + 32] = f2bf(O1[rg] * li[rg]);
    }
}

// ---------------------------------------------------------------------------
// Workspace layout (43 MB total — inside the PROVEN 44 MB envelope).
//   [ 0, 8)  q_wsb
//   [ 8,16)  k_wsb
//   [16,24)  v_wsb
//   [24,32)  x_bf (dead after gemm_qkv)
//   [32,40)  a_wsb (bf16 [b,t,512], written directly by attn)
//   [40,40.5) relb
//   [41,42.5) WT_all    [42.5,43) WoutT
// ---------------------------------------------------------------------------
extern "C" void kernel_launch(void* const* d_in, const int* in_sizes, int n_in,
                              void* d_out, int out_size, void* d_ws, size_t ws_size,
                              hipStream_t stream)
{
    const float* x    = (const float*)d_in[0];
    const float* Wq   = (const float*)d_in[1];
    const float* bq   = (const float*)d_in[2];
    const float* Wkv  = (const float*)d_in[3];
    const float* bkv  = (const float*)d_in[4];
    const float* Wout = (const float*)d_in[5];
    const float* bout = (const float*)d_in[6];
    const float* rel  = (const float*)d_in[7];
    float* out = (float*)d_out;

    char* ws = (char*)d_ws;
    const size_t MB = 1024 * 1024;
    u16*   q_wsb  = (u16*)(ws);                           // 8 MB [b,h,t,d]
    u16*   k_wsb  = (u16*)(ws + 8 * MB);                  // 8 MB [b,h,t,d]
    u16*   v_wsb  = (u16*)(ws + 16 * MB);                 // 8 MB [b,h,d,t]
    u16*   x_bf   = (u16*)(ws + 24 * MB);                 // 8 MB [8192,512]
    u16*   a_wsb  = (u16*)(ws + 32 * MB);                 // 8 MB [b,t,512]
    u16*   relb   = (u16*)(ws + 40 * MB);                 // 128 KB
    u16*   WT_all = (u16*)(ws + 41 * MB);                 // 1.5 MB [1536,512]
    u16*   WoutT  = (u16*)(ws + 42 * MB + 512 * 1024);    // 512 KB [512,512]

    // A: dtype conversions
    cvt_misc<<<(NX4 + NR4 + 255) / 256, 256, 0, stream>>>(x, rel, x_bf, relb);
    cvt_wT<<<256, 256, 0, stream>>>(Wq, Wkv, Wout, WT_all, WT_all + 512 * 512, WoutT);

    // B: fused qkv projection, LDS-staged m97-style (R17)
    gemm_qkv<<<dim3(64, 12), 256, 0, stream>>>(
        x_bf, WT_all, bq, bkv, q_wsb, k_wsb, v_wsb);

    // C: attention, merged-bperm single-epoch skew (R19)
    attn_mfma<<<dim3(64, 8), 256, 0, stream>>>(
        q_wsb, k_wsb, v_wsb, relb, a_wsb);

    // D: out projection, LDS-staged m97-style (R17)
    gemm_out<<<dim3(64, 4), 256, 0, stream>>>(a_wsb, WoutT, bout, out);
}

// Round 8
// 208.131 us; speedup vs baseline: 1.0948x; 1.0685x over previous
//
#include <hip/hip_runtime.h>

// Problem constants
#define BB 8
#define TT 1024
#define NH 8
#define HD 64
#define QT 128   // q rows per attention block (R12 proven structure)

typedef unsigned short u16;
typedef __attribute__((ext_vector_type(8))) short bf16x8;
typedef __attribute__((ext_vector_type(16))) float f32x16;

__device__ __forceinline__ float bf2f(u16 s) {
    union { unsigned u; float f; } v; v.u = ((unsigned)s) << 16; return v.f;
}
__device__ __forceinline__ u16 f2bf(float f) {
    union { float f; unsigned u; } v; v.f = f;
    unsigned r = (v.u + 0x7FFFu + ((v.u >> 16) & 1u)) >> 16;
    return (u16)r;
}
__device__ __forceinline__ float bperm(int byte_idx, float v) {
    union { float f; int i; } a; a.f = v;
    union { int i; float f; } b;
    b.i = __builtin_amdgcn_ds_bpermute(byte_idx, a.i);
    return b.f;
}
// async global->LDS, 16B/lane. LDS dest = wave-uniform base + lane*16.
__device__ __forceinline__ void gload_lds16(const u16* g, u16* l) {
    __builtin_amdgcn_global_load_lds(
        (const __attribute__((address_space(1))) unsigned int*)g,
        (__attribute__((address_space(3))) unsigned int*)l, 16, 0, 0);
}

#define MFMA(a, b, c) __builtin_amdgcn_mfma_f32_32x32x16_bf16((a), (b), (c), 0, 0, 0)

// ---------------------------------------------------------------------------
// R20: fused conversion kernel (one launch instead of two).
// Blocks [0, 4161): flat fp32->bf16 for x and rel_emb.
// Blocks [4161, 4417): W transpose fp32->bf16 (Wq, Wkv, Wout).
// ---------------------------------------------------------------------------
#define NX4 1048576   // x float4 chunks
#define NR4 16400     // rel float4 chunks
#define CVT_MISC_BLOCKS 4161
__global__ __launch_bounds__(256) void cvt_all(
    const float* __restrict__ x, const float* __restrict__ rel,
    const float* __restrict__ Wq, const float* __restrict__ Wkv,
    const float* __restrict__ Wout,
    u16* __restrict__ xb, u16* __restrict__ relb,
    u16* __restrict__ WqT, u16* __restrict__ WkvT, u16* __restrict__ WoutT)
{
    __shared__ float tile[64][65];
    const int tid = threadIdx.x;

    if (blockIdx.x < CVT_MISC_BLOCKS) {
        size_t i = (size_t)blockIdx.x * 256 + tid;
        const float* src; u16* dst;
        if (i < NX4) { src = x; dst = xb; }
        else {
            i -= NX4;
            if (i >= NR4) return;
            src = rel; dst = relb;
        }
        float4 f = *(const float4*)(src + i * 4);
        ushort4 o;
        o.x = f2bf(f.x); o.y = f2bf(f.y); o.z = f2bf(f.z); o.w = f2bf(f.w);
        *(ushort4*)(dst + i * 4) = o;
        return;
    }

    int bid = blockIdx.x - CVT_MISC_BLOCKS;
    const float* W; u16* Wt; int N, kt, ct;
    if (bid < 64)       { W = Wq;   Wt = WqT;   N = 512;  kt = (bid >> 3) * 64; ct = (bid & 7) * 64; }
    else if (bid < 192) { bid -= 64;  W = Wkv;  Wt = WkvT; N = 1024; kt = (bid >> 4) * 64; ct = (bid & 15) * 64; }
    else                { bid -= 192; W = Wout; Wt = WoutT; N = 512;  kt = (bid >> 3) * 64; ct = (bid & 7) * 64; }

#pragma unroll
    for (int i = 0; i < 16; i++) {
        int e = tid + i * 256;
        int r = e >> 6, c = e & 63;
        tile[r][c] = W[(size_t)(kt + r) * N + ct + c];
    }
    __syncthreads();
#pragma unroll
    for (int i = 0; i < 16; i++) {
        int e = tid + i * 256;
        int rr = e >> 6, cc = e & 63;   // output row = original col
        Wt[(size_t)(ct + rr) * 512 + kt + cc] = f2bf(tile[cc][rr]);
    }
}

// ---------------------------------------------------------------------------
// R17 GEMM K-loop core: m97-style LDS staging. 128x128 tile, 4 waves 2x2,
// acc[2][2] of 32x32 MFMA. global_load_lds width=16; XOR-swizzled source
// (rule 21); 2-barrier loop.
// ---------------------------------------------------------------------------
#define GEMM_STAGE(As, Bs, Abase, Bbase, k0)                                   \
    {                                                                          \
        const int wb16 = (tid & 192) * 8; /* wave base, u16 units (64*16B) */  \
        _Pragma("unroll")                                                      \
        for (int i = 0; i < 4; i++) {                                          \
            int slot = i * 256 + tid;                                          \
            int row = slot >> 3;                                               \
            int c16 = (slot & 7) ^ (row & 7);                                  \
            gload_lds16(Abase + (size_t)row * 512 + (k0) + c16 * 8,            \
                        As + i * 2048 + wb16);                                 \
            gload_lds16(Bbase + (size_t)row * 512 + (k0) + c16 * 8,            \
                        Bs + i * 2048 + wb16);                                 \
        }                                                                      \
    }

#define GEMM_COMPUTE(As, Bs, ar_base, br_base)                                 \
    {                                                                          \
        _Pragma("unroll")                                                      \
        for (int ks = 0; ks < 4; ks++) {                                       \
            bf16x8 a0, a1, b0, b1;                                             \
            {                                                                  \
                int r0_ = (ar_base), r1_ = (ar_base) + 32;                     \
                int q0_ = (br_base), q1_ = (br_base) + 32;                     \
                a0 = *(const bf16x8*)(As + r0_ * 64 +                          \
                                      (((2 * ks + lh) ^ (r0_ & 7)) * 8));      \
                a1 = *(const bf16x8*)(As + r1_ * 64 +                          \
                                      (((2 * ks + lh) ^ (r1_ & 7)) * 8));      \
                b0 = *(const bf16x8*)(Bs + q0_ * 64 +                          \
                                      (((2 * ks + lh) ^ (q0_ & 7)) * 8));      \
                b1 = *(const bf16x8*)(Bs + q1_ * 64 +                          \
                                      (((2 * ks + lh) ^ (q1_ & 7)) * 8));      \
            }                                                                  \
            acc[0][0] = MFMA(a0, b0, acc[0][0]);                               \
            acc[0][1] = MFMA(a0, b1, acc[0][1]);                               \
            acc[1][0] = MFMA(a1, b0, acc[1][0]);                               \
            acc[1][1] = MFMA(a1, b1, acc[1][1]);                               \
        }                                                                      \
    }

// ---------------------------------------------------------------------------
// Fused qkv projection. Grid (64, 12), block 256. Output split q/k/v with
// the R9-proven epilogue (q scaled 0.125/ln2; v transposed [b,h,d,t]).
// ---------------------------------------------------------------------------
__global__ __launch_bounds__(256) void gemm_qkv(
    const u16* __restrict__ A, const u16* __restrict__ Bt,
    const float* __restrict__ bq, const float* __restrict__ bkv,
    u16* __restrict__ oq, u16* __restrict__ ok, u16* __restrict__ ov)
{
    __shared__ __align__(16) u16 As[128 * 64];
    __shared__ __align__(16) u16 Bs[128 * 64];

    const int tid = threadIdx.x;
    const int lane = tid & 63, w = tid >> 6;
    const int l31 = lane & 31, lh = lane >> 5;
    const int wr = w & 1, wc = w >> 1;
    const int row0 = blockIdx.x * 128 + 64 * wr;
    const int c0g  = blockIdx.y * 128 + 64 * wc;

    const u16* Abase = A  + (size_t)blockIdx.x * 128 * 512;
    const u16* Bbase = Bt + (size_t)blockIdx.y * 128 * 512;
    const int ar_base = 64 * wr + l31;
    const int br_base = 64 * wc + l31;

    f32x16 acc[2][2];
#pragma unroll
    for (int i = 0; i < 2; i++)
#pragma unroll
        for (int j = 0; j < 2; j++)
#pragma unroll
            for (int e = 0; e < 16; e++) acc[i][j][e] = 0.f;

    for (int kk = 0; kk < 8; kk++) {
        GEMM_STAGE(As, Bs, Abase, Bbase, kk * 64);
        __syncthreads();
        GEMM_COMPUTE(As, Bs, ar_base, br_base);
        __syncthreads();
    }

    const int rbase = 4 * lh;
#pragma unroll
    for (int ri = 0; ri < 2; ri++) {
#pragma unroll
        for (int ci = 0; ci < 2; ci++) {
            const int r0 = row0 + 32 * ri;
            const int gc = c0g + 32 * ci + l31;
            if (gc < 512) {            // q (scaled by 0.125 * 1/ln2)
                const float bv = bq[gc];
                const int h = gc >> 6, d = gc & 63;
#pragma unroll
                for (int rg = 0; rg < 16; rg++) {
                    int gr = r0 + (rg & 3) + 8 * (rg >> 2) + rbase;
                    int b = gr >> 10, t = gr & 1023;
                    oq[(((size_t)b * NH + h) * TT + t) * HD + d] =
                        f2bf((acc[ri][ci][rg] + bv) * 0.18033688f);
                }
            } else if (gc < 1024) {    // k
                const float bv = bkv[gc - 512];
                const int h = (gc - 512) >> 6, d = gc & 63;
#pragma unroll
                for (int rg = 0; rg < 16; rg++) {
                    int gr = r0 + (rg & 3) + 8 * (rg >> 2) + rbase;
                    int b = gr >> 10, t = gr & 1023;
                    ok[(((size_t)b * NH + h) * TT + t) * HD + d] =
                        f2bf(acc[ri][ci][rg] + bv);
                }
            } else {                   // v, transposed [b,h,d,t]
                const float bv = bkv[gc - 512];
                const int vcol = gc - 1024;
                const int h = vcol >> 6, d = vcol & 63;
                const int b = r0 >> 10;
                const int t0 = (r0 & 1023) + rbase;
                size_t base = (((size_t)b * NH + h) * HD + d) * TT;
#pragma unroll
                for (int g = 0; g < 4; g++) {
                    ushort4 p;
                    p.x = f2bf(acc[ri][ci][4 * g + 0] + bv);
                    p.y = f2bf(acc[ri][ci][4 * g + 1] + bv);
                    p.z = f2bf(acc[ri][ci][4 * g + 2] + bv);
                    p.w = f2bf(acc[ri][ci][4 * g + 3] + bv);
                    *(ushort4*)&ov[base + t0 + 8 * g] = p;
                }
            }
        }
    }
}

// ---------------------------------------------------------------------------
// Out projection: out = a[8192,512] @ Wout + bout, fp32 result.
// R20: 128x64 tile, grid (64, 8) = 512 blocks = 2/CU (was 256 = 1/CU ->
// 1 wave/SIMD; now 2). Same LDS-staged K-loop, acc pair per wave.
// ---------------------------------------------------------------------------
__global__ __launch_bounds__(256) void gemm_out(
    const u16* __restrict__ A, const u16* __restrict__ Bt,
    const float* __restrict__ bias, float* __restrict__ of)
{
    __shared__ __align__(16) u16 As[128 * 64];
    __shared__ __align__(16) u16 Bs[64 * 64];

    const int tid = threadIdx.x;
    const int lane = tid & 63, w = tid >> 6;
    const int l31 = lane & 31, lh = lane >> 5;
    const int wr = w & 1, wc = w >> 1;
    const int row0 = blockIdx.x * 128 + 64 * wr;

    const u16* Abase = A  + (size_t)blockIdx.x * 128 * 512;
    const u16* Bbase = Bt + (size_t)blockIdx.y * 64 * 512;
    const int ar_base = 64 * wr + l31;
    const int br_base = 32 * wc + l31;

    f32x16 acc0, acc1;
#pragma unroll
    for (int i = 0; i < 16; i++) { acc0[i] = 0.f; acc1[i] = 0.f; }

    for (int kk = 0; kk < 8; kk++) {
        {
            const int wb16 = (tid & 192) * 8;
#pragma unroll
            for (int i = 0; i < 4; i++) {
                int slot = i * 256 + tid;
                int row = slot >> 3;
                int c16 = (slot & 7) ^ (row & 7);
                gload_lds16(Abase + (size_t)row * 512 + kk * 64 + c16 * 8,
                            As + i * 2048 + wb16);
            }
#pragma unroll
            for (int i = 0; i < 2; i++) {
                int slot = i * 256 + tid;
                int row = slot >> 3;
                int c16 = (slot & 7) ^ (row & 7);
                gload_lds16(Bbase + (size_t)row * 512 + kk * 64 + c16 * 8,
                            Bs + i * 2048 + wb16);
            }
        }
        __syncthreads();
#pragma unroll
        for (int ks = 0; ks < 4; ks++) {
            int r0_ = ar_base, r1_ = ar_base + 32, q0_ = br_base;
            bf16x8 a0 = *(const bf16x8*)(As + r0_ * 64 +
                                         (((2 * ks + lh) ^ (r0_ & 7)) * 8));
            bf16x8 a1 = *(const bf16x8*)(As + r1_ * 64 +
                                         (((2 * ks + lh) ^ (r1_ & 7)) * 8));
            bf16x8 b0 = *(const bf16x8*)(Bs + q0_ * 64 +
                                         (((2 * ks + lh) ^ (q0_ & 7)) * 8));
            acc0 = MFMA(a0, b0, acc0);
            acc1 = MFMA(a1, b0, acc1);
        }
        __syncthreads();
    }

    const int rbase = 4 * lh;
    const int gcol = blockIdx.y * 64 + 32 * wc + l31;
    const float bv = bias[gcol];
#pragma unroll
    for (int rg = 0; rg < 16; rg++) {
        int gr = row0 + (rg & 3) + 8 * (rg >> 2) + rbase;
        of[(size_t)gr * 512 + gcol]        = acc0[rg] + bv;
        of[(size_t)(gr + 32) * 512 + gcol] = acc1[rg] + bv;
    }
}

// ---------------------------------------------------------------------------
// MFMA flash attention (R16 + R19 + R20).
// R20: REL SLIDING-WINDOW REUSE. Tile mt+1's gt2 rel rows
// (pbb-m0n+64+l31) are EXACTLY tile mt's gt0 rows (pbb-m0+l31), clamps
// included. Rotate rf[8..11] <- rf[0..3] (16 movs) and load only
// gt0/gt1 (8 loads) per tile: -4 VMEM + addressing, and rel loads
// issue right after the G chains (nearly a full tile of flight).
// R18's hash offset removed (null; with mt=it the it=15 prep is a dummy).
// Per-tile VMEM: rf 8 -> vf 8 -> kf 8 (FIFO vmcnt leaves later in flight).
// Spill tripwire: WRITE_SIZE 8192 KB; numerics tripwire: absmax 4.88e-4
// (bitwise-identical math).
// ---------------------------------------------------------------------------
__global__ __launch_bounds__(256) void attn_mfma(
    const u16* __restrict__ q_ws, const u16* __restrict__ k_ws,
    const u16* __restrict__ v_ws, const u16* __restrict__ relb,
    u16* __restrict__ attn_out)
{
    __shared__ __align__(16) u16 GPs[4][32 * 104];   // per-wave P tile

    const int tid  = threadIdx.x;
    const int lane = tid & 63;
    const int w    = tid >> 6;
    const int l31  = lane & 31;
    const int lh   = lane >> 5;
    const int bh   = blockIdx.x;
    const int n0   = blockIdx.y * QT;

    // Q A-fragments (rows n0+32w+l31), held in registers for all 16 m-tiles
    bf16x8 a_q[4];
    {
        const u16* qp = q_ws + (((size_t)bh * TT) + n0 + 32 * w + l31) * HD + 8 * lh;
#pragma unroll
        for (int ks = 0; ks < 4; ks++)
            a_q[ks] = *(const bf16x8*)(qp + 16 * ks);
    }

    f32x16 O0, O1;
    float li[16];
#pragma unroll
    for (int i = 0; i < 16; i++) { O0[i] = 0.f; O1[i] = 0.f; li[i] = 0.f; }

    u16* Gw = GPs[w];
    const int rbase = 4 * lh;
    const u16* kbase = k_ws + (size_t)bh * TT * HD;
    const u16* vbase = v_ws + (size_t)bh * HD * TT;
    const int pbb = n0 + 449 + 32 * w;   // rel-pos base for m0 = 0

    // ---- mt-invariant precomputes
    f32x16 zvec;
#pragma unroll
    for (int i = 0; i < 16; i++) zvec[i] = 0.f;
    int bidx16[16];
#pragma unroll
    for (int rg = 0; rg < 16; rg++) {
        int r = (rg & 3) + 8 * (rg >> 2) + rbase;
        bidx16[rg] = (((lh << 5) | ((r - l31 + 31) & 31))) << 2;
    }

    // ---- preloop: kf(0) load+consume -> S(0); then rf(0) all 12, kf(1)
    bf16x8 kf[8], rf[12];
#pragma unroll
    for (int ks = 0; ks < 4; ks++) {
        const int doff = 16 * ks + 8 * lh;
        kf[2 * ks]     = *(const bf16x8*)(kbase + (size_t)l31 * HD + doff);
        kf[2 * ks + 1] = *(const bf16x8*)(kbase + (size_t)(l31 + 32) * HD + doff);
    }
    f32x16 S0 = MFMA(a_q[0], kf[0], zvec);
    f32x16 S1 = MFMA(a_q[0], kf[1], zvec);
#pragma unroll
    for (int ks = 1; ks < 4; ks++) {
        S0 = MFMA(a_q[ks], kf[2 * ks], S0);
        S1 = MFMA(a_q[ks], kf[2 * ks + 1], S1);
    }
    {   // rf(0): all 3 gt blocks
#pragma unroll
        for (int gt = 0; gt < 3; gt++) {
            int p = pbb + 32 * gt + l31;
            p = p < 0 ? 0 : (p > 1024 ? 1024 : p);
            const u16* rb = relb + (size_t)p * HD;
#pragma unroll
            for (int ks = 0; ks < 4; ks++)
                rf[4 * gt + ks] = *(const bf16x8*)(rb + 16 * ks + 8 * lh);
        }
    }
    {   // kf(1)
        const u16* kb = kbase + (size_t)64 * HD;
#pragma unroll
        for (int ks = 0; ks < 4; ks++) {
            const int doff = 16 * ks + 8 * lh;
            kf[2 * ks]     = *(const bf16x8*)(kb + (size_t)l31 * HD + doff);
            kf[2 * ks + 1] = *(const bf16x8*)(kb + (size_t)(l31 + 32) * HD + doff);
        }
    }

    for (int mt = 0; mt < 16; mt++) {
        const int m0 = mt * 64;
        // On entry: S0/S1 = QK(mt) done; rf = rel(mt) in flight; kf = K(mt+1).

        // ---- G phase: 3 INDEPENDENT chains, pipelined together
        f32x16 gA = MFMA(a_q[0], rf[0], zvec);
        f32x16 gB = MFMA(a_q[0], rf[4], zvec);
        f32x16 gC = MFMA(a_q[0], rf[8], zvec);
#pragma unroll
        for (int ks = 1; ks < 4; ks++) {
            gA = MFMA(a_q[ks], rf[ks], gA);
            gB = MFMA(a_q[ks], rf[4 + ks], gB);
            gC = MFMA(a_q[ks], rf[8 + ks], gC);
        }

        // ---- rel rotate + next-tile loads (R20): gt2(mt+1) == gt0(mt)
        rf[8]  = rf[0];
        rf[9]  = rf[1];
        rf[10] = rf[2];
        rf[11] = rf[3];
        {
            const int m0n = (mt < 15) ? m0 + 64 : 0;   // mt=15 prep: dummy
            const int pb = pbb - m0n;
            int p0 = pb + l31;       p0 = p0 < 0 ? 0 : (p0 > 1024 ? 1024 : p0);
            int p1 = pb + 32 + l31;  p1 = p1 < 0 ? 0 : (p1 > 1024 ? 1024 : p1);
            const u16* rb0 = relb + (size_t)p0 * HD;
            const u16* rb1 = relb + (size_t)p1 * HD;
#pragma unroll
            for (int ks = 0; ks < 4; ks++) {
                rf[ks]     = *(const bf16x8*)(rb0 + 16 * ks + 8 * lh);
                rf[4 + ks] = *(const bf16x8*)(rb1 + 16 * ks + 8 * lh);
            }
        }

        // ---- merged skew: source-lane select + ONE bperm epoch (32 ops)
#pragma unroll
        for (int rg = 0; rg < 16; rg++) {
            int r = (rg & 3) + 8 * (rg >> 2) + rbase;
            float mS0 = (l31 >= r) ? gB[rg] : gC[rg];
            float mS1 = (l31 >= r) ? gA[rg] : gB[rg];
            S0[rg] += bperm(bidx16[rg], mS0);
            S1[rg] += bperm(bidx16[rg], mS1);
        }

        // ---- vf(mt) issue (latency covered by exp/pack + S-next QK)
        bf16x8 vf[8];
        {
            const u16* vb = vbase + m0;
#pragma unroll
            for (int ms = 0; ms < 4; ms++) {
                const int mg = 2 * ms + lh;
                vf[2 * ms]     = *(const bf16x8*)(vb + (size_t)l31 * TT + mg * 8);
                vf[2 * ms + 1] = *(const bf16x8*)(vb + (size_t)(l31 + 32) * TT + mg * 8);
            }
        }

        // ---- streaming softmax + P pack (q pre-scaled by 1/ln2 -> 2^x)
#pragma unroll
        for (int rg = 0; rg < 16; rg++) {
            float e0, e1;
            asm("v_exp_f32 %0, %1" : "=v"(e0) : "v"(S0[rg]));
            asm("v_exp_f32 %0, %1" : "=v"(e1) : "v"(S1[rg]));
            li[rg] += e0 + e1;
            unsigned pk;
            asm("v_cvt_pk_bf16_f32 %0, %1, %2" : "=v"(pk) : "v"(e0), "v"(e1));
            int r = (rg & 3) + 8 * (rg >> 2) + rbase;
            Gw[r * 104 + (((l31 >> 3) ^ (r & 7)) * 8) + (l31 & 7)] = (u16)pk;
            Gw[r * 104 + (((((l31 + 32) >> 3)) ^ (r & 7)) * 8) + (l31 & 7)] =
                (u16)(pk >> 16);
        }

        // ---- S(mt+1) = QK(kf): overlaps softmax/pack + PV LDS turnaround
        if (mt < 15) {
            __builtin_amdgcn_s_setprio(1);
            S0 = MFMA(a_q[0], kf[0], zvec);
            S1 = MFMA(a_q[0], kf[1], zvec);
#pragma unroll
            for (int ks = 1; ks < 4; ks++) {
                S0 = MFMA(a_q[ks], kf[2 * ks], S0);
                S1 = MFMA(a_q[ks], kf[2 * ks + 1], S1);
            }
            __builtin_amdgcn_s_setprio(0);
            // issue kf(mt+2)
            const int m0k = (mt < 14) ? m0 + 128 : 0;  // wrap: valid, unused
            const u16* kb = kbase + (size_t)m0k * HD;
#pragma unroll
            for (int ks = 0; ks < 4; ks++) {
                const int doff = 16 * ks + 8 * lh;
                kf[2 * ks]     = *(const bf16x8*)(kb + (size_t)l31 * HD + doff);
                kf[2 * ks + 1] = *(const bf16x8*)(kb + (size_t)(l31 + 32) * HD + doff);
            }
        }

        // ---- O += P V from vf (waits vf; kf prefetch stays in flight)
        __builtin_amdgcn_s_setprio(1);
#pragma unroll
        for (int ms = 0; ms < 4; ms++) {
            const int mg = 2 * ms + lh;
            bf16x8 a_p = *(const bf16x8*)&Gw[l31 * 104 + ((mg ^ (l31 & 7)) * 8)];
            O0 = MFMA(a_p, vf[2 * ms], O0);
            O1 = MFMA(a_p, vf[2 * ms + 1], O1);
        }
        __builtin_amdgcn_s_setprio(0);
    }

    // ---- epilogue: reduce li across the 32 lanes holding each row
#pragma unroll
    for (int rg = 0; rg < 16; rg++) {
        float rs = li[rg];
        rs += __shfl_xor(rs, 1);
        rs += __shfl_xor(rs, 2);
        rs += __shfl_xor(rs, 4);
        rs += __shfl_xor(rs, 8);
        rs += __shfl_xor(rs, 16);
        li[rg] = 1.0f / rs;
    }

    // write bf16 [b, t, h*64 + d]
    const int b = bh >> 3, h = bh & 7;
    u16* ob = attn_out + ((size_t)b * TT + n0 + 32 * w) * 512 + h * 64;
#pragma unroll
    for (int rg = 0; rg < 16; rg++) {
        int r = (rg & 3) + 8 * (rg >> 2) + rbase;
        ob[(size_t)r * 512 + l31]      = f2bf(O0[rg] * li[rg]);
        ob[(size_t)r * 512 + l31 + 32] = f2bf(O1[rg] * li[rg]);
    }
}

// ---------------------------------------------------------------------------
// Workspace layout (43 MB total — inside the PROVEN 44 MB envelope).
//   [ 0, 8)  q_wsb
//   [ 8,16)  k_wsb
//   [16,24)  v_wsb
//   [24,32)  x_bf (dead after gemm_qkv)
//   [32,40)  a_wsb (bf16 [b,t,512], written directly by attn)
//   [40,40.5) relb
//   [41,42.5) WT_all    [42.5,43) WoutT
// ---------------------------------------------------------------------------
extern "C" void kernel_launch(void* const* d_in, const int* in_sizes, int n_in,
                              void* d_out, int out_size, void* d_ws, size_t ws_size,
                              hipStream_t stream)
{
    const float* x    = (const float*)d_in[0];
    const float* Wq   = (const float*)d_in[1];
    const float* bq   = (const float*)d_in[2];
    const float* Wkv  = (const float*)d_in[3];
    const float* bkv  = (const float*)d_in[4];
    const float* Wout = (const float*)d_in[5];
    const float* bout = (const float*)d_in[6];
    const float* rel  = (const float*)d_in[7];
    float* out = (float*)d_out;

    char* ws = (char*)d_ws;
    const size_t MB = 1024 * 1024;
    u16*   q_wsb  = (u16*)(ws);                           // 8 MB [b,h,t,d]
    u16*   k_wsb  = (u16*)(ws + 8 * MB);                  // 8 MB [b,h,t,d]
    u16*   v_wsb  = (u16*)(ws + 16 * MB);                 // 8 MB [b,h,d,t]
    u16*   x_bf   = (u16*)(ws + 24 * MB);                 // 8 MB [8192,512]
    u16*   a_wsb  = (u16*)(ws + 32 * MB);                 // 8 MB [b,t,512]
    u16*   relb   = (u16*)(ws + 40 * MB);                 // 128 KB
    u16*   WT_all = (u16*)(ws + 41 * MB);                 // 1.5 MB [1536,512]
    u16*   WoutT  = (u16*)(ws + 42 * MB + 512 * 1024);    // 512 KB [512,512]

    // A: fused dtype conversions (one launch, R20)
    cvt_all<<<CVT_MISC_BLOCKS + 256, 256, 0, stream>>>(
        x, rel, Wq, Wkv, Wout, x_bf, relb,
        WT_all, WT_all + 512 * 512, WoutT);

    // B: fused qkv projection, LDS-staged m97-style (R17)
    gemm_qkv<<<dim3(64, 12), 256, 0, stream>>>(
        x_bf, WT_all, bq, bkv, q_wsb, k_wsb, v_wsb);

    // C: attention, merged-bperm skew + rel sliding-window reuse (R20)
    attn_mfma<<<dim3(64, 8), 256, 0, stream>>>(
        q_wsb, k_wsb, v_wsb, relb, a_wsb);

    // D: out projection, 128x64 tiles, 2 blocks/CU (R20)
    gemm_out<<<dim3(64, 8), 256, 0, stream>>>(a_wsb, WoutT, bout, out);
}